// Round 1
// baseline (1224.708 us; speedup 1.0000x reference)
//
#include <hip/hip_runtime.h>
#include <hip/hip_bf16.h>
#include <math.h>

#define LN 4
#define B_ 8
#define D_ 2048
#define DI 4096
#define N_ 128
#define H_ 64
#define P_ 64
#define K_ 4
#define M_ 8
#define V_ 50288
#define CCH (DI + 2*N_)           // 4352
#define DOUT (2*DI + 2*N_ + H_)   // 8512
#define EPSF 1e-5f

__device__ inline float wave_sum(float v) {
  #pragma unroll
  for (int off = 32; off > 0; off >>= 1) v += __shfl_xor(v, off, 64);
  return v;
}

// ---------------- embed gather ----------------
__global__ void k_embed(const int* __restrict__ ids, const float* __restrict__ emb,
                        float* __restrict__ res) {
  int idx = blockIdx.x * 256 + threadIdx.x;   // 16384 total
  int b = idx >> 11, d = idx & 2047;
  res[idx] = emb[(size_t)ids[b] * D_ + d];
}

// ---------------- rmsnorm (one block per row) ----------------
__global__ void k_rmsnorm(const float* __restrict__ in, const float* __restrict__ w,
                          float* __restrict__ out, int D) {
  __shared__ float lds[8];
  int b = blockIdx.x;
  const float* row = in + (size_t)b * D;
  float ss = 0.f;
  for (int i = threadIdx.x; i < D; i += blockDim.x) { float v = row[i]; ss += v * v; }
  float wsum = wave_sum(ss);
  int lane = threadIdx.x & 63, wid = threadIdx.x >> 6;
  if (lane == 0) lds[wid] = wsum;
  __syncthreads();
  int nw = blockDim.x >> 6;
  float tot = 0.f;
  for (int i = 0; i < nw; ++i) tot += lds[i];
  float scale = rsqrtf(tot / (float)D + EPSF);
  for (int i = threadIdx.x; i < D; i += blockDim.x) out[(size_t)b * D + i] = row[i] * scale * w[i];
}

// ---------------- in_proj: (8x2048)@(2048x8512), split-K with atomics --------
// grid = 9 j-tiles * 32 k-tiles = 288 blocks, 256 threads, each thread 4 cols
__global__ void k_inproj(const float* __restrict__ xn, const float* __restrict__ W,
                         float* __restrict__ zx) {
  __shared__ float xs[8][64];
  int jt = blockIdx.x % 9, kt = blockIdx.x / 9;
  int k0 = kt * 64;
  for (int i = threadIdx.x; i < 8 * 64; i += 256) {
    int r = i >> 6, kk = i & 63;
    xs[r][kk] = xn[r * D_ + k0 + kk];
  }
  __syncthreads();
  int j = jt * 1024 + threadIdx.x * 4;
  if (j >= DOUT) return;
  float4 acc[8];
  #pragma unroll
  for (int r = 0; r < 8; ++r) acc[r] = make_float4(0.f, 0.f, 0.f, 0.f);
  const float* Wp = W + (size_t)k0 * DOUT + j;
  for (int kk = 0; kk < 64; ++kk) {
    float4 w4 = *reinterpret_cast<const float4*>(Wp + (size_t)kk * DOUT);
    #pragma unroll
    for (int r = 0; r < 8; ++r) {
      float xv = xs[r][kk];
      acc[r].x += w4.x * xv; acc[r].y += w4.y * xv;
      acc[r].z += w4.z * xv; acc[r].w += w4.w * xv;
    }
  }
  #pragma unroll
  for (int r = 0; r < 8; ++r) {
    atomicAdd(&zx[r * DOUT + j + 0], acc[r].x);
    atomicAdd(&zx[r * DOUT + j + 1], acc[r].y);
    atomicAdd(&zx[r * DOUT + j + 2], acc[r].z);
    atomicAdd(&zx[r * DOUT + j + 3], acc[r].w);
  }
}

// ---------------- conv step + dt/dA + softmax(W_mc), fused small kernel ------
// grid = 136 blocks * 256 = 34816 = B*CCH
__global__ void k_conv_dt(const float* __restrict__ zx, const float* __restrict__ conv_state,
                          const float* __restrict__ conv_w, const float* __restrict__ conv_b,
                          const float* __restrict__ A_log, const float* __restrict__ dt_bias,
                          const float* __restrict__ W_mc,
                          float* __restrict__ xbc, float* __restrict__ dts,
                          float* __restrict__ dav, float* __restrict__ wmc) {
  int gid = blockIdx.x * 256 + threadIdx.x;
  if (gid < B_ * CCH) {
    int b = gid / CCH, c = gid % CCH;
    const float* cs = conv_state + ((size_t)b * CCH + c) * K_;
    const float* cw = conv_w + (size_t)c * K_;
    float xnew = zx[b * DOUT + DI + c];
    float v = cs[1] * cw[0] + cs[2] * cw[1] + cs[3] * cw[2] + xnew * cw[3] + conv_b[c];
    xbc[gid] = v / (1.f + expf(-v));   // silu
  }
  if (gid < B_ * H_) {
    int b = gid >> 6, h = gid & 63;
    float x = zx[b * DOUT + DI + CCH + h] + dt_bias[h];
    float sp = (x > 20.f) ? x : log1pf(expf(x));   // softplus
    dts[gid] = sp;
    dav[gid] = expf(-expf(A_log[h]) * sp);
  }
  if (gid == 0) {
    float mx = -1e30f;
    for (int i = 0; i < M_ + 1; ++i) mx = fmaxf(mx, W_mc[i]);
    float e[M_ + 1], s = 0.f;
    for (int i = 0; i < M_ + 1; ++i) { e[i] = expf(W_mc[i] - mx); s += e[i]; }
    for (int i = 0; i < M_ + 1; ++i) wmc[i] = e[i] / s;
  }
}

// ---------------- state update + MC fuse + y : one wave per (b,h,p) ----------
// grid = 8192 blocks * 256 (4 waves/block)
__global__ void k_state(const float* __restrict__ xbc, const float* __restrict__ dts,
                        const float* __restrict__ dav, const float* __restrict__ Dp_,
                        const float* __restrict__ wmc, const float* __restrict__ ssm,
                        const float* __restrict__ cached, float* __restrict__ y) {
  int wg = blockIdx.x * 4 + (threadIdx.x >> 6);
  int lane = threadIdx.x & 63;
  int b = wg >> 12;                 // / (H*P)
  int hp = wg & 4095;
  int h = hp >> 6, p = hp & 63;
  float xv  = xbc[b * CCH + h * 64 + p];
  float dtv = dts[b * 64 + h];
  float da  = dav[b * 64 + h];
  float w8 = wmc[8];
  float wm[8];
  #pragma unroll
  for (int m = 0; m < 8; ++m) wm[m] = wmc[m];
  const float* sp = ssm + ((size_t)b * H_ + h) * (P_ * N_) + (size_t)p * N_;
  const float* cp = cached + (size_t)b * (M_ * H_ * P_ * N_) + (size_t)h * (P_ * N_) + (size_t)p * N_;
  float acc = 0.f;
  #pragma unroll
  for (int n2 = 0; n2 < 2; ++n2) {
    int n = n2 * 64 + lane;
    float Bn = xbc[b * CCH + DI + n];
    float Cn = xbc[b * CCH + DI + N_ + n];
    float sv = sp[n] * da + dtv * Bn * xv;
    float f = w8 * sv;
    #pragma unroll
    for (int m = 0; m < 8; ++m) f += wm[m] * cp[(size_t)m * (H_ * P_ * N_) + n];
    acc += f * Cn;
  }
  acc = wave_sum(acc);
  if (lane == 0) y[b * DI + h * 64 + p] = acc + Dp_[h] * xv;
}

// ---------------- gated RMS norm: y*silu(z) then rms over 4096 ---------------
__global__ void k_gatednorm(const float* __restrict__ y, const float* __restrict__ zx,
                            const float* __restrict__ mnw, float* __restrict__ yg) {
  __shared__ float lds[8];
  int b = blockIdx.x;
  float tv[16];
  float ss = 0.f;
  #pragma unroll
  for (int t = 0; t < 16; ++t) {
    int i = threadIdx.x + t * 256;
    float z = zx[b * DOUT + i];
    float v = y[b * DI + i] * (z / (1.f + expf(-z)));
    tv[t] = v; ss += v * v;
  }
  float wsum = wave_sum(ss);
  int lane = threadIdx.x & 63, wid = threadIdx.x >> 6;
  if (lane == 0) lds[wid] = wsum;
  __syncthreads();
  float tot = lds[0] + lds[1] + lds[2] + lds[3];
  float scale = rsqrtf(tot / (float)DI + EPSF);
  #pragma unroll
  for (int t = 0; t < 16; ++t) {
    int i = threadIdx.x + t * 256;
    yg[b * DI + i] = tv[t] * scale * mnw[i];
  }
}

// ---------------- out_proj: (8x4096)@(4096x2048) += res, split-K -------------
// grid = 2 j-tiles * 128 k-tiles = 256 blocks
__global__ void k_outproj(const float* __restrict__ yg, const float* __restrict__ W,
                          float* __restrict__ res) {
  __shared__ float xs[8][32];
  int jt = blockIdx.x & 1, kt = blockIdx.x >> 1;
  int k0 = kt * 32;
  for (int i = threadIdx.x; i < 8 * 32; i += 256) {
    int r = i >> 5, kk = i & 31;
    xs[r][kk] = yg[r * DI + k0 + kk];
  }
  __syncthreads();
  int j = jt * 1024 + threadIdx.x * 4;
  float4 acc[8];
  #pragma unroll
  for (int r = 0; r < 8; ++r) acc[r] = make_float4(0.f, 0.f, 0.f, 0.f);
  const float* Wp = W + (size_t)k0 * D_ + j;
  for (int kk = 0; kk < 32; ++kk) {
    float4 w4 = *reinterpret_cast<const float4*>(Wp + (size_t)kk * D_);
    #pragma unroll
    for (int r = 0; r < 8; ++r) {
      float xv = xs[r][kk];
      acc[r].x += w4.x * xv; acc[r].y += w4.y * xv;
      acc[r].z += w4.z * xv; acc[r].w += w4.w * xv;
    }
  }
  #pragma unroll
  for (int r = 0; r < 8; ++r) {
    atomicAdd(&res[r * D_ + j + 0], acc[r].x);
    atomicAdd(&res[r * D_ + j + 1], acc[r].y);
    atomicAdd(&res[r * D_ + j + 2], acc[r].z);
    atomicAdd(&res[r * D_ + j + 3], acc[r].w);
  }
}

// ---------------- logits: one wave per vocab row, xn staged in LDS -----------
__global__ void k_logits(const float* __restrict__ xn, const float* __restrict__ emb,
                         float* __restrict__ out) {
  __shared__ float4 xs[8][512];   // 64 KB = full (8,2048) xn
  for (int i = threadIdx.x; i < 8 * 512; i += 256)
    xs[i >> 9][i & 511] = reinterpret_cast<const float4*>(xn)[i];
  __syncthreads();
  int wid = threadIdx.x >> 6, lane = threadIdx.x & 63;
  for (int v = blockIdx.x * 4 + wid; v < V_; v += gridDim.x * 4) {
    const float4* ep = reinterpret_cast<const float4*>(emb + (size_t)v * D_);
    float acc[8] = {0.f, 0.f, 0.f, 0.f, 0.f, 0.f, 0.f, 0.f};
    #pragma unroll
    for (int i = 0; i < 8; ++i) {
      int c = i * 64 + lane;
      float4 e = ep[c];
      #pragma unroll
      for (int r = 0; r < 8; ++r) {
        float4 x4 = xs[r][c];
        acc[r] += e.x * x4.x + e.y * x4.y + e.z * x4.z + e.w * x4.w;
      }
    }
    #pragma unroll
    for (int r = 0; r < 8; ++r) {
      float s = wave_sum(acc[r]);
      if (lane == 0) out[(size_t)r * V_ + v] = s;
    }
  }
}

extern "C" void kernel_launch(void* const* d_in, const int* in_sizes, int n_in,
                              void* d_out, int out_size, void* d_ws, size_t ws_size,
                              hipStream_t stream) {
  const int*   ids    = (const int*)  d_in[0];
  const float* emb    = (const float*)d_in[1];
  const float* inW    = (const float*)d_in[2];
  const float* convW  = (const float*)d_in[3];
  const float* convB  = (const float*)d_in[4];
  const float* Alog   = (const float*)d_in[5];
  const float* dtB    = (const float*)d_in[6];
  const float* Dpar   = (const float*)d_in[7];
  const float* mnw    = (const float*)d_in[8];
  const float* outW   = (const float*)d_in[9];
  const float* lnw    = (const float*)d_in[10];
  const float* nfw    = (const float*)d_in[11];
  const float* Wmc    = (const float*)d_in[12];
  const float* convS  = (const float*)d_in[13];
  const float* ssmS   = (const float*)d_in[14];
  const float* cached = (const float*)d_in[15];
  float* out = (float*)d_out;
  float* ws  = (float*)d_ws;

  float* res = ws;            // 16384 floats
  float* xn  = ws + 16384;    // 16384
  float* zx  = ws + 32768;    // 68096
  float* xbc = ws + 100864;   // 34816
  float* dts = ws + 135680;   // 512
  float* dav = ws + 136192;   // 512
  float* wmc = ws + 136704;   // 16 (use 64 slot)
  float* y   = ws + 136768;   // 32768
  float* yg  = ws + 169536;   // 32768  -> total 202304 floats (~0.81 MB)

  k_embed<<<64, 256, 0, stream>>>(ids, emb, res);
  for (int l = 0; l < LN; ++l) {
    k_rmsnorm<<<8, 256, 0, stream>>>(res, lnw + (size_t)l * D_, xn, D_);
    hipMemsetAsync(zx, 0, (size_t)B_ * DOUT * sizeof(float), stream);
    k_inproj<<<288, 256, 0, stream>>>(xn, inW + (size_t)l * D_ * DOUT, zx);
    k_conv_dt<<<136, 256, 0, stream>>>(zx,
        convS + (size_t)l * B_ * CCH * K_, convW + (size_t)l * CCH * K_,
        convB + (size_t)l * CCH, Alog + l * H_, dtB + l * H_, Wmc + l * (M_ + 1),
        xbc, dts, dav, wmc);
    k_state<<<8192, 256, 0, stream>>>(xbc, dts, dav, Dpar + l * H_, wmc,
        ssmS + (size_t)l * B_ * H_ * P_ * N_,
        cached + (size_t)l * B_ * M_ * H_ * P_ * N_, y);
    k_gatednorm<<<8, 256, 0, stream>>>(y, zx, mnw + (size_t)l * DI, yg);
    k_outproj<<<256, 256, 0, stream>>>(yg, outW + (size_t)l * DI * D_, res);
  }
  k_rmsnorm<<<8, 256, 0, stream>>>(res, nfw, xn, D_);
  k_logits<<<2048, 256, 0, stream>>>(xn, emb, out);
}